// Round 3
// baseline (202.826 us; speedup 1.0000x reference)
//
#include <hip/hip_runtime.h>
#include <hip/hip_bf16.h>
#include <hip/hip_fp16.h>

typedef __attribute__((ext_vector_type(8))) short bf16x8;   // 8 bf16 = 4 VGPRs
typedef __attribute__((ext_vector_type(4))) float f32x4;
typedef unsigned short u16;
typedef unsigned int uint;

#define Bb 2
#define Tt 2048
#define Dd 1024
#define Hh 16

#define EXP2F(x) __builtin_amdgcn_exp2f(x)

__device__ inline u16 f2bf(float f) {
    union { float f; uint u; } v; v.f = f;
    uint r = v.u + 0x7fffu + ((v.u >> 16) & 1u);   // RNE
    return (u16)(r >> 16);
}
__device__ inline uint fbits(float f) { union { float f; uint u; } v; v.f = f; return v.u; }
__device__ inline u16 f2h(float f) { return __half_as_ushort(__float2half(f)); }
__device__ inline float h2f(u16 u) { return __half2float(__ushort_as_half(u)); }

// async global->LDS, 16B per lane; dest wave-uniform base + lane*16.
__device__ inline void glds16(const u16* g, u16* l) {
    __builtin_amdgcn_global_load_lds(
        (const __attribute__((address_space(1))) void*)g,
        (__attribute__((address_space(3))) void*)l,
        16, 0, 0);
}

// ---------------------------------------------------------------------------
// prep: fused {fp32->bf16 cvt of x} + {transpose_cvt Wqkv} + {transpose_cvt
// Wout} in one dispatch. Role by blockIdx.x.
// ---------------------------------------------------------------------------
__global__ __launch_bounds__(256) void prep(
    const float* __restrict__ x, u16* __restrict__ xb,
    const float* __restrict__ Wqkv, u16* __restrict__ WqT,
    const float* __restrict__ Wout, u16* __restrict__ WoT)
{
    __shared__ float tile[64][65];
    const int bid = blockIdx.x;
    const int tid = threadIdx.x;

    if (bid < 2048) {   // elementwise cvt role
        const size_t i = ((size_t)bid * 256 + tid) * 8;
        const float4 a = *(const float4*)&x[i];
        const float4 b = *(const float4*)&x[i + 4];
        uint4 o;
        o.x = (uint)f2bf(a.x) | ((uint)f2bf(a.y) << 16);
        o.y = (uint)f2bf(a.z) | ((uint)f2bf(a.w) << 16);
        o.z = (uint)f2bf(b.x) | ((uint)f2bf(b.y) << 16);
        o.w = (uint)f2bf(b.z) | ((uint)f2bf(b.w) << 16);
        *(uint4*)&xb[i] = o;
        return;
    }

    const float* W; u16* Wt; int N, bx, by;
    const int K = 1024;
    if (bid < 2048 + 768) {
        const int r = bid - 2048;
        W = Wqkv; Wt = WqT; N = 3072; bx = r % 48; by = r / 48;
    } else {
        const int r = bid - 2816;
        W = Wout; Wt = WoT; N = 1024; bx = r & 15; by = r >> 4;
    }
    const int k0 = by * 64, n0 = bx * 64;
    const int tr = tid >> 4;
    const int tc = (tid & 15) * 4;

    #pragma unroll
    for (int i = 0; i < 4; ++i) {
        const float4 v = *(const float4*)&W[(size_t)(k0 + tr + i * 16) * N + n0 + tc];
        tile[tr + i * 16][tc + 0] = v.x;
        tile[tr + i * 16][tc + 1] = v.y;
        tile[tr + i * 16][tc + 2] = v.z;
        tile[tr + i * 16][tc + 3] = v.w;
    }
    __syncthreads();
    #pragma unroll
    for (int i = 0; i < 4; ++i) {
        ushort4 o;
        o.x = f2bf(tile[tc + 0][tr + i * 16]);
        o.y = f2bf(tile[tc + 1][tr + i * 16]);
        o.z = f2bf(tile[tc + 2][tr + i * 16]);
        o.w = f2bf(tile[tc + 3][tr + i * 16]);
        *(ushort4*)&Wt[(size_t)(n0 + tr + i * 16) * K + k0 + tc] = o;
    }
}

// ---------------------------------------------------------------------------
// gemm256: 256x256 8-phase schedule (T3+T4+T5, m201 structure) for the QKV
// projection. 512 thr = 8 waves (2M x 4N); per-wave C = 128x64 = 8x4 frags.
// BK=64. LDS: A,B each [par][half][128x64] half-double-buffered (64KB+64KB)
// + 16KB dummy tail sink = 144 KB -> 1 block/CU by design.
// Schedule per K-tile t (4 phases), quadrants m0n0 -> m1n0 -> m1n1 -> m0n1
// (A-m0 frags kept in regs so phase 3 has no ds_reads):
//   ph0: ds_read A-m0(8)+B-n0(4) | stage B-H0(t+1) | bar;lgkm0;MFMA16 | bar
//   ph1: ds_read A-m1(8)         | stage B-H1(t+1) | bar;lgkm0;MFMA16 | bar
//   ph2: ds_read B-n1(4)         | stage A-H0(t+2) | bar;lgkm0;MFMA16 | bar
//   ph3: (no reads)              | stage A-H1(t+2) | bar;MFMA16;vmcnt(4);bar
// Counted vmcnt(4) once per tile, NEVER 0 in loop (T4). Safety: each LDS
// region's last read (barrier-sealed) precedes its re-stage by >=1 phase;
// tile t's 8 loads are all older than the newest-4 at phi(t-1,3)'s vmcnt(4).
// Tail stages -> dummy region (uniform counts); vmcnt(0) before epilogue.
// Swizzle: row=64 bf16=8 slots of 16B; store slot s holds k-chunk s^(row&7)
// via pre-swizzled global source (rule 21); read slot=(ks*4+quad)^(m16&7):
// within 16 lanes, 8 distinct slots x 4 banks = 32 banks, 2-way = free.
// Epilogue = MODE-1 semantics (Q,K -> qkvb; V -> vg transposed).
// ---------------------------------------------------------------------------
__global__ __launch_bounds__(512, 2) void gemm256(
    const u16* __restrict__ A, const u16* __restrict__ Bt,
    const float* __restrict__ bias, u16* __restrict__ C,
    u16* __restrict__ vg, int K)
{
    __shared__ u16 As[2 * 2 * 8192];   // [par][half][128*64]  64 KB
    __shared__ u16 Bs[2 * 2 * 8192];   //                      64 KB
    __shared__ u16 Du[8192];           // dummy tail sink      16 KB

    const int tid  = threadIdx.x;
    const int lane = tid & 63;
    const int w    = tid >> 6;           // 0..7
    const int wm   = w >> 2, wn = w & 3; // 2M x 4N
    const int quad = lane >> 4;
    const int m16  = lane & 15;
    const int row0 = blockIdx.y * 256;
    const int col0 = blockIdx.x * 256;

    const int sr9  = tid >> 3;           // 0..63 (staging row within call)
    const int s8   = tid & 7;
    const int cXor = (s8 ^ (sr9 & 7)) * 8;   // pre-swizzled k-chunk (elems)
    const int wdst = w * 512;                // wave-uniform LDS stage base

    const int nT = K >> 6;               // 16

    // per-thread staging source bases (row sr9 of half 0, call 0)
    const u16* sA0 = A  + (size_t)(row0 + sr9) * K + cXor;
    const u16* sB0 = Bt + (size_t)(col0 + sr9) * K + cXor;
    const size_t d64K = (size_t)64 * K;  // 64 rows

    // slot byte offsets for fragment reads (u16 units)
    const int sl0 = ((0 * 4 + quad) ^ (m16 & 7)) * 8;
    const int sl1 = ((1 * 4 + quad) ^ (m16 & 7)) * 8;

    f32x4 acc[8][4];
    #pragma unroll
    for (int i = 0; i < 8; ++i)
        #pragma unroll
        for (int j = 0; j < 4; ++j) acc[i][j] = (f32x4){0.f, 0.f, 0.f, 0.f};

    #define STAGE_A(TT, H) do {                                            \
        const int t_ = (TT);                                               \
        const int tc_ = t_ < nT ? t_ : nT - 1;                             \
        const size_t so_ = (size_t)((H) * 128) * K + (size_t)tc_ * 64;     \
        u16* d0_ = (t_ < nT) ? &As[(((t_ & 1) * 2 + (H)) * 8192) + wdst]   \
                             : &Du[wdst];                                  \
        u16* d1_ = (t_ < nT) ? &As[(((t_ & 1) * 2 + (H)) * 8192) + 4096 + wdst] \
                             : &Du[4096 + wdst];                           \
        glds16(sA0 + so_, d0_);                                            \
        glds16(sA0 + so_ + d64K, d1_);                                     \
    } while (0)

    #define STAGE_B(TT, H) do {                                            \
        const int t_ = (TT);                                               \
        const int tc_ = t_ < nT ? t_ : nT - 1;                             \
        const size_t so_ = (size_t)((H) * 128) * K + (size_t)tc_ * 64;     \
        u16* d0_ = (t_ < nT) ? &Bs[(((t_ & 1) * 2 + (H)) * 8192) + wdst]   \
                             : &Du[wdst];                                  \
        u16* d1_ = (t_ < nT) ? &Bs[(((t_ & 1) * 2 + (H)) * 8192) + 4096 + wdst] \
                             : &Du[4096 + wdst];                           \
        glds16(sB0 + so_, d0_);                                            \
        glds16(sB0 + so_ + d64K, d1_);                                     \
    } while (0)

    // prologue: A(0), B(0), A(1) = 12 glds; wait all but A(1)'s 4.
    STAGE_A(0, 0); STAGE_A(0, 1);
    STAGE_B(0, 0); STAGE_B(0, 1);
    STAGE_A(1, 0); STAGE_A(1, 1);
    asm volatile("s_waitcnt vmcnt(4)" ::: "memory");
    __builtin_amdgcn_s_barrier();

    #define MFMA_ACC(M, N_, AV, BV)                                        \
        acc[M][N_] = __builtin_amdgcn_mfma_f32_16x16x32_bf16(              \
            (AV)[0], (BV)[0], acc[M][N_], 0, 0, 0);                        \
        acc[M][N_] = __builtin_amdgcn_mfma_f32_16x16x32_bf16(              \
            (AV)[1], (BV)[1], acc[M][N_], 0, 0, 0)

    for (int t = 0; t < nT; ++t) {
        const int par   = t & 1;
        const int baseA = (par * 2 + wm) * 8192;
        const int baseB = (par * 2 + (wn >> 1)) * 8192 + (wn & 1) * 4096;

        // ---- phase 0: read A-m0 + B-n0, stage B-H0(t+1), compute m0n0 ----
        bf16x8 a0[4][2], b0[2][2];
        #pragma unroll
        for (int mt = 0; mt < 4; ++mt) {
            const int ro = baseA + (mt * 16 + m16) * 64;
            a0[mt][0] = *(const bf16x8*)&As[ro + sl0];
            a0[mt][1] = *(const bf16x8*)&As[ro + sl1];
        }
        #pragma unroll
        for (int nt = 0; nt < 2; ++nt) {
            const int ro = baseB + (nt * 16 + m16) * 64;
            b0[nt][0] = *(const bf16x8*)&Bs[ro + sl0];
            b0[nt][1] = *(const bf16x8*)&Bs[ro + sl1];
        }
        STAGE_B(t + 1, 0);
        __builtin_amdgcn_s_barrier();
        asm volatile("s_waitcnt lgkmcnt(0)" ::: "memory");
        __builtin_amdgcn_sched_barrier(0);
        __builtin_amdgcn_s_setprio(1);
        #pragma unroll
        for (int mt = 0; mt < 4; ++mt) {
            MFMA_ACC(mt, 0, a0[mt], b0[0]);
            MFMA_ACC(mt, 1, a0[mt], b0[1]);
        }
        __builtin_amdgcn_s_setprio(0);
        __builtin_amdgcn_s_barrier();

        // ---- phase 1: read A-m1, stage B-H1(t+1), compute m1n0 ----
        bf16x8 a1[4][2];
        #pragma unroll
        for (int mt = 0; mt < 4; ++mt) {
            const int ro = baseA + (64 + mt * 16 + m16) * 64;
            a1[mt][0] = *(const bf16x8*)&As[ro + sl0];
            a1[mt][1] = *(const bf16x8*)&As[ro + sl1];
        }
        STAGE_B(t + 1, 1);
        __builtin_amdgcn_s_barrier();
        asm volatile("s_waitcnt lgkmcnt(0)" ::: "memory");
        __builtin_amdgcn_sched_barrier(0);
        __builtin_amdgcn_s_setprio(1);
        #pragma unroll
        for (int mt = 0; mt < 4; ++mt) {
            MFMA_ACC(4 + mt, 0, a1[mt], b0[0]);
            MFMA_ACC(4 + mt, 1, a1[mt], b0[1]);
        }
        __builtin_amdgcn_s_setprio(0);
        __builtin_amdgcn_s_barrier();

        // ---- phase 2: read B-n1, stage A-H0(t+2), compute m1n1 ----
        bf16x8 b1[2][2];
        #pragma unroll
        for (int nt = 0; nt < 2; ++nt) {
            const int ro = baseB + (32 + nt * 16 + m16) * 64;
            b1[nt][0] = *(const bf16x8*)&Bs[ro + sl0];
            b1[nt][1] = *(const bf16x8*)&Bs[ro + sl1];
        }
        STAGE_A(t + 2, 0);
        __builtin_amdgcn_s_barrier();
        asm volatile("s_waitcnt lgkmcnt(0)" ::: "memory");
        __builtin_amdgcn_sched_barrier(0);
        __builtin_amdgcn_s_setprio(1);
        #pragma unroll
        for (int mt = 0; mt < 4; ++mt) {
            MFMA_ACC(4 + mt, 2, a1[mt], b1[0]);
            MFMA_ACC(4 + mt, 3, a1[mt], b1[1]);
        }
        __builtin_amdgcn_s_setprio(0);
        __builtin_amdgcn_s_barrier();

        // ---- phase 3: no reads (a0 kept), stage A-H1(t+2), compute m0n1 ----
        STAGE_A(t + 2, 1);
        __builtin_amdgcn_s_barrier();
        __builtin_amdgcn_sched_barrier(0);
        __builtin_amdgcn_s_setprio(1);
        #pragma unroll
        for (int mt = 0; mt < 4; ++mt) {
            MFMA_ACC(mt, 2, a0[mt], b1[0]);
            MFMA_ACC(mt, 3, a0[mt], b1[1]);
        }
        __builtin_amdgcn_s_setprio(0);
        asm volatile("s_waitcnt vmcnt(4)" ::: "memory");
        __builtin_amdgcn_s_barrier();
    }
    #undef STAGE_A
    #undef STAGE_B
    #undef MFMA_ACC

    asm volatile("s_waitcnt vmcnt(0)" ::: "memory");   // drain dummy tail

    #pragma unroll
    for (int mt = 0; mt < 8; ++mt) {
        #pragma unroll
        for (int nt = 0; nt < 4; ++nt) {
            const int row = row0 + wm * 128 + mt * 16 + quad * 4;
            const int col = col0 + wn * 64 + nt * 16 + m16;
            const float bv = bias[col];
            #pragma unroll
            for (int r = 0; r < 4; ++r) {
                const float v = acc[mt][nt][r] + bv;
                if (col0 < 2048) {   // Q,K region (256-blocks never straddle)
                    C[(size_t)(row + r) * 2048 + col] = f2bf(v);
                } else {             // V: write transposed into vg[b][h][d][T]
                    const int hcol = col - 2048;
                    const int hh = hcol >> 6, dd = hcol & 63;
                    const int bb = (row + r) >> 11, tt = (row + r) & 2047;
                    vg[((size_t)(bb * Hh + hh) * 64 + dd) * Tt + tt] = f2bf(v);
                }
            }
        }
    }
}

// ---------------------------------------------------------------------------
// gemm_bt MODE 0 (128^2, verified 2-barrier structure) for the output proj:
// N=1024 -> 256-wide tiles would give only 64 blocks; 128^2 keeps 256 blocks.
// ---------------------------------------------------------------------------
__global__ __launch_bounds__(256) void gemm_bt0(
    const u16* __restrict__ A, const u16* __restrict__ Bt,
    const float* __restrict__ bias, float* __restrict__ C,
    int M, int N, int K)
{
    __shared__ u16 As[2][128 * 32];
    __shared__ u16 Bs[2][128 * 32];

    const int tid  = threadIdx.x;
    const int lane = tid & 63;
    const int w    = tid >> 6;
    const int wm   = w >> 1, wn = w & 1;
    const int quad = lane >> 4;
    const int m16  = lane & 15;
    const int row0 = blockIdx.y * 128;
    const int col0 = blockIdx.x * 128;

    f32x4 acc[4][4];
    #pragma unroll
    for (int i = 0; i < 4; ++i)
        #pragma unroll
        for (int j = 0; j < 4; ++j) acc[i][j] = (f32x4){0.f, 0.f, 0.f, 0.f};

    const int sr  = tid >> 2, sqs = tid & 3;
    const int sq  = sqs ^ ((sr >> 1) & 3);
    const int ldsw = w * 512;
    const int slot = quad ^ ((m16 >> 1) & 3);

    const int nIter = K >> 5;

    glds16(&A [(size_t)(row0 + sr) * K + sq * 8],       &As[0][ldsw]);
    glds16(&A [(size_t)(row0 + sr + 64) * K + sq * 8],  &As[0][2048 + ldsw]);
    glds16(&Bt[(size_t)(col0 + sr) * K + sq * 8],       &Bs[0][ldsw]);
    glds16(&Bt[(size_t)(col0 + sr + 64) * K + sq * 8],  &Bs[0][2048 + ldsw]);

    for (int it = 0; it < nIter; ++it) {
        const int cb = it & 1;
        __syncthreads();

        if (it + 1 < nIter) {
            const int ko = (it + 1) << 5;
            const int nb = cb ^ 1;
            glds16(&A [(size_t)(row0 + sr) * K + ko + sq * 8],       &As[nb][ldsw]);
            glds16(&A [(size_t)(row0 + sr + 64) * K + ko + sq * 8],  &As[nb][2048 + ldsw]);
            glds16(&Bt[(size_t)(col0 + sr) * K + ko + sq * 8],       &Bs[nb][ldsw]);
            glds16(&Bt[(size_t)(col0 + sr + 64) * K + ko + sq * 8],  &Bs[nb][2048 + ldsw]);
        }

        bf16x8 af[4], bfr[4];
        #pragma unroll
        for (int mt = 0; mt < 4; ++mt)
            af[mt] = *(const bf16x8*)&As[cb][(wm * 64 + mt * 16 + m16) * 32 + slot * 8];
        #pragma unroll
        for (int nt = 0; nt < 4; ++nt)
            bfr[nt] = *(const bf16x8*)&Bs[cb][(wn * 64 + nt * 16 + m16) * 32 + slot * 8];
        #pragma unroll
        for (int mt = 0; mt < 4; ++mt)
            #pragma unroll
            for (int nt = 0; nt < 4; ++nt)
                acc[mt][nt] = __builtin_amdgcn_mfma_f32_16x16x32_bf16(
                    af[mt], bfr[nt], acc[mt][nt], 0, 0, 0);
    }

    #pragma unroll
    for (int mt = 0; mt < 4; ++mt) {
        #pragma unroll
        for (int nt = 0; nt < 4; ++nt) {
            const int row = row0 + wm * 64 + mt * 16 + quad * 4;
            const int col = col0 + wn * 64 + nt * 16 + m16;
            const float bv = bias[col];
            #pragma unroll
            for (int r = 0; r < 4; ++r)
                C[(size_t)(row + r) * N + col] = acc[mt][nt][r] + bv;
        }
    }
}

// ---------------------------------------------------------------------------
// Flash causal attention v6: split-K(2) + fixed-offset softmax + T5 setprio.
// ---------------------------------------------------------------------------
__global__ __launch_bounds__(256, 4) void attn_split(
    const u16* __restrict__ qkvb, const u16* __restrict__ vglob,
    u16* __restrict__ wsO, float* __restrict__ wsL)
{
    const int hb  = blockIdx.x;
    const int h   = hb & 15, b = hb >> 4;
    const int qt  = 15 - (blockIdx.y >> 1);   // heavy-first
    const int half = blockIdx.y & 1;
    const int tid = threadIdx.x;
    const int lane = tid & 63, w = tid >> 6;
    const int quad = lane >> 4, m16 = lane & 15;

    __shared__ u16 KV[2][64 * 64];       // [0]=K, [1]=Vt, 16 KB
    __shared__ u16 Pt[128 * 72];         // 18 KB

    const int q0 = qt * 128;
    const size_t qkbase = (size_t)(b * Tt) * 2048;
    const size_t vbase  = (size_t)((b * Hh + h) * 64) * Tt;

    const int sr8 = tid >> 3;                // 0..31
    const int sq8 = (tid & 7) ^ (sr8 & 7);
    const int ldsw = w * 512;
    const int slot = quad ^ (m16 & 7);       // ks=0 read slot; ks=1 -> ^4

    // Q^T B-frags, loop-invariant, from global:
    bf16x8 qb[2][2];
    #pragma unroll
    for (int nt = 0; nt < 2; ++nt)
        #pragma unroll
        for (int ks = 0; ks < 2; ++ks)
            qb[nt][ks] = *(const bf16x8*)&qkvb[
                qkbase + (size_t)(q0 + w * 32 + nt * 16 + m16) * 2048
                + h * 64 + ks * 32 + quad * 8];

    f32x4 o[4][2];
    #pragma unroll
    for (int ct = 0; ct < 4; ++ct)
        #pragma unroll
        for (int nt = 0; nt < 2; ++nt) o[ct][nt] = (f32x4){0.f, 0.f, 0.f, 0.f};
    float ls[2] = {0.f, 0.f};
    const float sc2 = 0.125f * 1.4426950408889634f;   // scale*log2(e)

    const int ntiles = 2 * qt + 2;
    for (int kt = half; kt < ntiles; kt += 2) {
        const int k0 = kt * 64;
        __syncthreads();   // all waves done with previous KV
        #pragma unroll
        for (int j = 0; j < 2; ++j) {
            const int row = j * 32 + sr8;
            glds16(&qkvb[qkbase + (size_t)(k0 + row) * 2048 + 1024 + h * 64 + sq8 * 8],
                   &KV[0][j * 2048 + ldsw]);
            glds16(&vglob[vbase + (size_t)row * Tt + k0 + sq8 * 8],
                   &KV[1][j * 2048 + ldsw]);
        }
        __syncthreads();   // vmcnt drain -> tiles visible

        if (k0 <= q0 + w * 32 + 31) {    // wave-uniform visibility
            const u16* Ks = KV[0];
            const u16* Vt = KV[1];

            // S^T = K · Q^T
            bf16x8 ak[4][2];
            #pragma unroll
            for (int mt = 0; mt < 4; ++mt) {
                const int ro = (mt * 16 + m16) * 64;
                ak[mt][0] = *(const bf16x8*)&Ks[ro + slot * 8];
                ak[mt][1] = *(const bf16x8*)&Ks[ro + (slot ^ 4) * 8];
            }
            f32x4 s[4][2];
            __builtin_amdgcn_s_setprio(1);
            #pragma unroll
            for (int mt = 0; mt < 4; ++mt)
                #pragma unroll
                for (int nt = 0; nt < 2; ++nt) {
                    f32x4 a = (f32x4){0.f, 0.f, 0.f, 0.f};
                    a = __builtin_amdgcn_mfma_f32_16x16x32_bf16(ak[mt][0], qb[nt][0], a, 0, 0, 0);
                    a = __builtin_amdgcn_mfma_f32_16x16x32_bf16(ak[mt][1], qb[nt][1], a, 0, 0, 0);
                    s[mt][nt] = a;
                }
            __builtin_amdgcn_s_setprio(0);

            // p = exp2(s*sc2 - 8), causal mask -> 0; accumulate l per-lane.
            const int qi0 = q0 + w * 32 + m16;
            const bool diag = (k0 + 63 > q0 + w * 32);
            #pragma unroll
            for (int mt = 0; mt < 4; ++mt)
                #pragma unroll
                for (int nt = 0; nt < 2; ++nt) {
                    float p[4];
                    const int kb = k0 + mt * 16 + quad * 4;
                    #pragma unroll
                    for (int r = 0; r < 4; ++r) {
                        float t = __builtin_fmaf(s[mt][nt][r], sc2, -8.0f);
                        if (diag) t = (kb + r <= qi0 + nt * 16) ? t : -1000.0f;
                        p[r] = EXP2F(t);
                    }
                    ls[nt] += (p[0] + p[1]) + (p[2] + p[3]);
                    uint2 pk;   // truncation-pack to bf16 pairs
                    pk.x = (fbits(p[0]) >> 16) | (fbits(p[1]) & 0xffff0000u);
                    pk.y = (fbits(p[2]) >> 16) | (fbits(p[3]) & 0xffff0000u);
                    *(uint2*)&Pt[(w * 32 + nt * 16 + m16) * 72 + mt * 16 + quad * 4] = pk;
                }

            // O^T += V^T · P^T  (same-wave Pt write->read)
            bf16x8 av[4][2], pb[2][2];
            #pragma unroll
            for (int ct = 0; ct < 4; ++ct) {
                const int ro = (ct * 16 + m16) * 64;
                av[ct][0] = *(const bf16x8*)&Vt[ro + slot * 8];
                av[ct][1] = *(const bf16x8*)&Vt[ro + (slot ^ 4) * 8];
            }
            #pragma unroll
            for (int nt = 0; nt < 2; ++nt)
                #pragma unroll
                for (int ks = 0; ks < 2; ++ks)
                    pb[nt][ks] = *(const bf16x8*)&Pt[(w * 32 + nt * 16 + m16) * 72 + ks * 32 + quad * 8];
            __builtin_amdgcn_s_setprio(1);
            #pragma unroll
            for (int ct = 0; ct < 4; ++ct)
                #pragma unroll
                for (int nt = 0; nt < 2; ++nt) {
                    o[ct][nt] = __builtin_amdgcn_mfma_f32_16x16x32_bf16(av[ct][0], pb[nt][0], o[ct][nt], 0, 0, 0);
                    o[ct][nt] = __builtin_amdgcn_mfma_f32_16x16x32_bf16(av[ct][1], pb[nt][1], o[ct][nt], 0, 0, 0);
                }
            __builtin_amdgcn_s_setprio(0);
        }
    }

    // epilogue: deferred l reduce (once), store fp16 O partial + fp32 l.
    #pragma unroll
    for (int nt = 0; nt < 2; ++nt) {
        ls[nt] += __shfl_xor(ls[nt], 16);
        ls[nt] += __shfl_xor(ls[nt], 32);
    }
    const int qrow = b * Tt + q0 + w * 32 + m16;
    if (quad == 0) {
        wsL[(half * Hh + h) * 4096 + qrow]      = ls[0];
        wsL[(half * Hh + h) * 4096 + qrow + 16] = ls[1];
    }
    #pragma unroll
    for (int ct = 0; ct < 4; ++ct)
        #pragma unroll
        for (int nt = 0; nt < 2; ++nt) {
            ushort4 pk;
            pk.x = f2h(o[ct][nt][0]);
            pk.y = f2h(o[ct][nt][1]);
            pk.z = f2h(o[ct][nt][2]);
            pk.w = f2h(o[ct][nt][3]);
            *(ushort4*)&wsO[((size_t)(half * 4096 + qrow + nt * 16)) * 1024
                            + h * 64 + ct * 16 + quad * 4] = pk;
        }
}

// ---------------------------------------------------------------------------
// combine: attb = bf16( (O0+O1) / (l0+l1) ), 8 elems/thread.
// ---------------------------------------------------------------------------
__global__ __launch_bounds__(256) void combine(
    const u16* __restrict__ wsO, const float* __restrict__ wsL,
    u16* __restrict__ attb)
{
    const int gi  = (blockIdx.x * 256 + threadIdx.x) * 8;
    const int row = gi >> 10;
    const int h   = (gi & 1023) >> 6;
    const float il = 1.0f / (wsL[h * 4096 + row] + wsL[(Hh + h) * 4096 + row]);
    const uint4 a = *(const uint4*)&wsO[gi];
    const uint4 c = *(const uint4*)&wsO[(size_t)4096 * 1024 + gi];
    const uint aw[4] = {a.x, a.y, a.z, a.w};
    const uint cw[4] = {c.x, c.y, c.z, c.w};
    uint ow[4];
    #pragma unroll
    for (int i = 0; i < 4; ++i) {
        const float r0 = (h2f((u16)(aw[i] & 0xffff)) + h2f((u16)(cw[i] & 0xffff))) * il;
        const float r1 = (h2f((u16)(aw[i] >> 16))    + h2f((u16)(cw[i] >> 16)))    * il;
        ow[i] = (uint)f2bf(r0) | ((uint)f2bf(r1) << 16);
    }
    uint4 o4; o4.x = ow[0]; o4.y = ow[1]; o4.z = ow[2]; o4.w = ow[3];
    *(uint4*)&attb[gi] = o4;
}

// ---------------------------------------------------------------------------
extern "C" void kernel_launch(void* const* d_in, const int* in_sizes, int n_in,
                              void* d_out, int out_size, void* d_ws, size_t ws_size,
                              hipStream_t stream) {
    const float* x    = (const float*)d_in[0];
    const float* Wqkv = (const float*)d_in[1];
    const float* bqkv = (const float*)d_in[2];
    const float* Wout = (const float*)d_in[3];
    const float* bout = (const float*)d_in[4];
    float* out = (float*)d_out;

    u16*   xb    = (u16*)d_ws;                               //  8 MB [4096][1024]
    u16*   WqT   = xb    + (size_t)4096 * 1024;              //  6 MB [3072][1024]
    u16*   WoT   = WqT   + (size_t)3072 * 1024;              //  2 MB [1024][1024]
    u16*   qkvb  = WoT   + (size_t)1024 * 1024;              // 16 MB [4096][2048] Q,K
    u16*   attb  = qkvb  + (size_t)4096 * 2048;              //  8 MB [4096][1024]
    u16*   vglob = attb  + (size_t)4096 * 1024;              //  8 MB [2][16][64][2048]
    u16*   wsO   = vglob + (size_t)4096 * 2048;              // 16 MB [2][4096][1024] fp16
    float* wsL   = (float*)(wsO + (size_t)2 * 4096 * 1024);  // 512 KB [2][16][4096]

    prep<<<dim3(2048 + 768 + 256), dim3(256), 0, stream>>>(
        x, xb, Wqkv, WqT, Wout, WoT);

    gemm256<<<dim3(3072 / 256, 4096 / 256), dim3(512), 0, stream>>>(
        xb, WqT, bqkv, qkvb, vglob, 1024);

    attn_split<<<dim3(Hh * Bb, 32), dim3(256), 0, stream>>>(qkvb, vglob, wsO, wsL);

    combine<<<dim3((4096 * 1024) / 8 / 256), dim3(256), 0, stream>>>(wsO, wsL, attb);

    gemm_bt0<<<dim3(1024 / 128, 4096 / 128), dim3(256), 0, stream>>>(
        attb, WoT, bout, out, 4096, 1024, 1024);
}